// Round 10
// baseline (336.578 us; speedup 1.0000x reference)
//
#include <hip/hip_runtime.h>
#include <stdint.h>

#define B_ 2
#define S_ 2048
#define H_ 12
#define D_ 64
#define HD_ 768
#define KEEP_HI 3865470464u           // 7549747u << 9 : bits < this  <=>  uniform < 0.9
#define C_INIT 0.15200309344504997f   // log2(1/0.9), folded into MFMA C-init
#define QSCALE 0.18033688011112042f   // 0.125 * log2(e)
#define NCHUNK 1572864u               // B*H*S*S / 64

typedef __attribute__((ext_vector_type(8))) _Float16 f16x8;
typedef __attribute__((ext_vector_type(4))) _Float16 f16x4;
typedef __attribute__((ext_vector_type(4))) float f32x4;

#define MFMA32 __builtin_amdgcn_mfma_f32_16x16x32_f16   // K=32, A/B = f16x8
#define MFMA16 __builtin_amdgcn_mfma_f32_16x16x16f16    // K=16, A/B = f16x4

__device__ __forceinline__ uint32_t rotl1(uint32_t x, int r) {
    // guaranteed single v_alignbit_b32: rotl(x,r) = ((x:x) >> (32-r))
    return __builtin_amdgcn_alignbit(x, x, 32 - r);
}

// JAX partitionable threefry, key (0,42), counter (0,i), out = x0^x1.
// (bit-exact verified rounds 2-9)
__device__ __forceinline__ uint32_t tf_bits(uint32_t i) {
    const uint32_t k1 = 42u, k2 = 0x1BD11BF0u;
    uint32_t x0 = 0u, x1 = i + k1;
#define TF_R(r) { x0 += x1; x1 = rotl1(x1, (r)); x1 ^= x0; }
    TF_R(13) TF_R(15) TF_R(26) TF_R(6)
    x0 += k1; x1 += k2 + 1u;
    TF_R(17) TF_R(29) TF_R(16) TF_R(24)
    x0 += k2; x1 += 2u;
    TF_R(13) TF_R(15) TF_R(26) TF_R(6)
    x1 += k1 + 3u;
    TF_R(17) TF_R(29) TF_R(16) TF_R(24)
    x0 += k1; x1 += k2 + 4u;
    TF_R(13) TF_R(15) TF_R(26) TF_R(6)
    x0 += k2; x1 += 5u;
#undef TF_R
    return x0 ^ x1;
}

// Pure-VALU streaming kernel: chunk c covers elements [64c, 64c+64);
// bit L of M[c] = keep(element 64c+L). 8192 waves x 192 chunks.
__global__ __launch_bounds__(256, 8)
void mask_kernel(uint64_t* __restrict__ M) {
    const int lane = threadIdx.x & 63;
    const uint32_t w = blockIdx.x * 4u + (threadIdx.x >> 6);   // 0..8191
    const uint32_t c0 = w * 192u;
    uint32_t i = c0 * 64u + (uint32_t)lane;
    for (uint32_t j = 0; j < 192u; ++j) {
        uint32_t bits = tf_bits(i);
        uint64_t bal = __ballot(bits < KEEP_HI);
        if (lane == 0) M[c0 + j] = bal;
        i += 64u;
    }
}

// R7 structure (best known): single-buffer LDS K/V tiles, 2 barriers/tile,
// P held in registers as the 16x16x16 B-fragment. Threefry replaced by a
// single uint64 mask load per (lane, tile).
template<int HALVES>
__global__ __launch_bounds__(256, 4)
void attn_kernel(const float* __restrict__ Q, const float* __restrict__ K,
                 const float* __restrict__ V, float* __restrict__ O,
                 float* __restrict__ W, const uint64_t* __restrict__ M) {
    constexpr int NT = 32 / HALVES;
    __shared__ __align__(16) _Float16 Kh[64][72];   // K tile [t][d]
    __shared__ __align__(16) _Float16 Vh[64][72];   // V^T tile [dd][t]

    const int tid  = threadIdx.x;
    const int lane = tid & 63;
    const int wid  = tid >> 6;
    const int g    = lane >> 4;
    const int sl   = lane & 15;

    const int bid  = blockIdx.x;
    const int half = bid / 768;
    const int bid2 = bid % 768;
    const int qb = bid2 & 31;
    const int bh = bid2 >> 5;
    const int h  = bh % H_;
    const int b  = bh / H_;
    const int kt0 = half * NT;

    const int s = qb * 64 + wid * 16 + sl;
    const size_t kvbase = (size_t)b * S_ * HD_ + (size_t)h * D_;
    const uint64_t* mrow = M + (size_t)(bh * S_ + s) * 32;   // 32 qwords per row

    // ---- Q fragment (B-operand of QK), scale 0.125*log2e, fp16 hi/lo ----
    f16x8 qh[2], ql[2];
    {
        const float* qp = Q + ((size_t)(b * S_ + s) * H_ + h) * D_;
#pragma unroll
        for (int ks = 0; ks < 2; ++ks) {
            int d0 = 32 * ks + 8 * g;
            float4 f0 = *reinterpret_cast<const float4*>(qp + d0);
            float4 f1 = *reinterpret_cast<const float4*>(qp + d0 + 4);
            float ff[8] = {f0.x, f0.y, f0.z, f0.w, f1.x, f1.y, f1.z, f1.w};
#pragma unroll
            for (int j = 0; j < 8; ++j) {
                float f = ff[j] * QSCALE;
                _Float16 hi = (_Float16)f;
                qh[ks][j] = hi;
                ql[ks][j] = (_Float16)(f - (float)hi);
            }
        }
    }

    // staging maps
    const int ktK = tid >> 2;            // K row t, 4 threads/row
    const int kd0 = (tid & 3) * 16;      // 16 consecutive d
    const int vdd = (tid & 31) * 2;      // V: dd pair
    const int vt0 = (tid >> 5) * 8;      // V: 8 consecutive t

    float4 kreg0, kreg1, kreg2, kreg3;
    float2 vreg[8];

#define LOADTILE(ktg_) do {                                                         \
        const float* kp = K + kvbase + (size_t)((ktg_) * 64 + ktK) * HD_ + kd0;     \
        kreg0 = *reinterpret_cast<const float4*>(kp);                               \
        kreg1 = *reinterpret_cast<const float4*>(kp + 4);                           \
        kreg2 = *reinterpret_cast<const float4*>(kp + 8);                           \
        kreg3 = *reinterpret_cast<const float4*>(kp + 12);                          \
        const float* vp = V + kvbase + (size_t)((ktg_) * 64 + vt0) * HD_ + vdd;     \
        _Pragma("unroll")                                                           \
        for (int j = 0; j < 8; ++j) vreg[j] = *reinterpret_cast<const float2*>(vp + j * HD_); \
    } while (0)

    LOADTILE(kt0);

    float lrun = 0.f;
    f32x4 outacc[4];
#pragma unroll
    for (int m = 0; m < 4; ++m) outacc[m] = (f32x4){0.f, 0.f, 0.f, 0.f};

    for (int ktl = 0; ktl < NT; ++ktl) {
        const int ktg = kt0 + ktl;
        if (ktl) __syncthreads();
        // ---- staged regs -> LDS (fp16) ----
        {
            float ff[16] = {kreg0.x, kreg0.y, kreg0.z, kreg0.w,
                            kreg1.x, kreg1.y, kreg1.z, kreg1.w,
                            kreg2.x, kreg2.y, kreg2.z, kreg2.w,
                            kreg3.x, kreg3.y, kreg3.z, kreg3.w};
            f16x8 h0, h1;
#pragma unroll
            for (int j = 0; j < 8; ++j) { h0[j] = (_Float16)ff[j]; h1[j] = (_Float16)ff[8 + j]; }
            *reinterpret_cast<f16x8*>(&Kh[ktK][kd0])     = h0;
            *reinterpret_cast<f16x8*>(&Kh[ktK][kd0 + 8]) = h1;
            f16x8 v0, v1;
#pragma unroll
            for (int j = 0; j < 8; ++j) { v0[j] = (_Float16)vreg[j].x; v1[j] = (_Float16)vreg[j].y; }
            *reinterpret_cast<f16x8*>(&Vh[vdd][vt0])     = v0;
            *reinterpret_cast<f16x8*>(&Vh[vdd + 1][vt0]) = v1;
        }
        __syncthreads();
        // mask qword for this (row, tile): bits [16m+4g+r]; issue early (L2 hit)
        const uint64_t bal = mrow[ktg];
        if (ktl + 1 < NT) LOADTILE(ktg + 1);   // overlap HBM/L2 latency with compute

        // ---- QK^T (swapped): sc[m][r] = log2e*S^T[t][s] + C, t=16m+4g+r, s=sl ----
        f32x4 sc[4];
#pragma unroll
        for (int m = 0; m < 4; ++m) sc[m] = (f32x4){C_INIT, C_INIT, C_INIT, C_INIT};
#pragma unroll
        for (int m = 0; m < 4; ++m) {
#pragma unroll
            for (int ks = 0; ks < 2; ++ks) {
                f16x8 ah = *reinterpret_cast<const f16x8*>(&Kh[16 * m + sl][8 * g + 32 * ks]);
                sc[m] = MFMA32(ah, qh[ks], sc[m], 0, 0, 0);
                sc[m] = MFMA32(ah, ql[ks], sc[m], 0, 0, 0);
            }
        }

        // ---- exp2 + mask-bit dropout + fp16 pack, AV via 16x16x16 ----
        const uint64_t balg = bal >> (4 * g);
#pragma unroll
        for (int m = 0; m < 4; ++m) {
            const uint32_t mb = (uint32_t)(balg >> (16 * m));
            f16x4 w;
#pragma unroll
            for (int r = 0; r < 4; ++r) {
                float e = exp2f(sc[m][r]);          // = exp(score)/0.9
                lrun += e;
                float pf = ((mb >> r) & 1u) ? e : 0.0f;
                w[r] = (_Float16)pf;                // RNE fp16 = astype(f16)
            }
#pragma unroll
            for (int md = 0; md < 4; ++md) {
                f16x4 va = *reinterpret_cast<const f16x4*>(&Vh[16 * md + sl][16 * m + 4 * g]);
                outacc[md] = MFMA16(va, w, outacc[md], 0, 0, 0);
            }
        }
    }
#undef LOADTILE

    // ---- row-sum L across the 4 lane groups ----
    lrun += __shfl_xor(lrun, 16);
    lrun += __shfl_xor(lrun, 32);

    if (HALVES == 1) {
        const float invL = 1.0f / (0.9f * lrun);   // lrun = L/0.9
        float* op = O + ((size_t)bh * S_ + s) * D_;
#pragma unroll
        for (int m = 0; m < 4; ++m) {
            int dd0 = 16 * m + 4 * g;
            float4 f = make_float4(outacc[m][0] * invL, outacc[m][1] * invL,
                                   outacc[m][2] * invL, outacc[m][3] * invL);
            *reinterpret_cast<float4*>(op + dd0) = f;
        }
    } else {
        float* wp = W + ((size_t)(half * 24 + bh) * S_ + s) * 68;
#pragma unroll
        for (int m = 0; m < 4; ++m) {
            int dd0 = 16 * m + 4 * g;
            float4 f = make_float4(outacc[m][0], outacc[m][1], outacc[m][2], outacc[m][3]);
            *reinterpret_cast<float4*>(wp + dd0) = f;
        }
        if (g == 0) wp[64] = lrun;
    }
}

__global__ __launch_bounds__(256)
void combine_kernel(const float* __restrict__ W, float* __restrict__ O) {
    const int row = blockIdx.x * 4 + (threadIdx.x >> 6);   // bh*2048 + s
    const int dd  = threadIdx.x & 63;
    const float* w0 = W + (size_t)row * 68;
    const float* w1 = W + ((size_t)(24 * 2048) + row) * 68;
    const float L = w0[64] + w1[64];                        // = L_true/0.9
    const float scale = 1.0f / (0.9f * L);
    O[(size_t)row * 64 + dd] = (w0[dd] + w1[dd]) * scale;
}

extern "C" void kernel_launch(void* const* d_in, const int* in_sizes, int n_in,
                              void* d_out, int out_size, void* d_ws, size_t ws_size,
                              hipStream_t stream) {
    const float* Q = (const float*)d_in[0];
    const float* K = (const float*)d_in[1];
    const float* V = (const float*)d_in[2];
    float* O = (float*)d_out;
    (void)in_sizes; (void)n_in; (void)out_size;

    const size_t mask_bytes = (size_t)NCHUNK * 8u;                     // 12.58 MB
    const size_t w_bytes    = (size_t)2 * 24 * 2048 * 68 * sizeof(float); // 26.7 MB

    uint64_t* M = (uint64_t*)d_ws;
    mask_kernel<<<dim3(2048), dim3(256), 0, stream>>>(M);

    if (ws_size >= mask_bytes + w_bytes) {
        float* W = (float*)((char*)d_ws + mask_bytes);
        attn_kernel<2><<<dim3(1536), dim3(256), 0, stream>>>(Q, K, V, O, W, M);
        combine_kernel<<<dim3(24 * 2048 / 4), dim3(256), 0, stream>>>(W, O);
    } else {
        attn_kernel<1><<<dim3(768), dim3(256), 0, stream>>>(Q, K, V, O, nullptr, M);
    }
}

// Round 11
// 236.835 us; speedup vs baseline: 1.4211x; 1.4211x over previous
//
#include <hip/hip_runtime.h>
#include <stdint.h>

#define B_ 2
#define S_ 2048
#define H_ 12
#define D_ 64
#define HD_ 768
#define KEEP_HI 3865470464u           // 7549747u << 9 : bits < this  <=>  uniform < 0.9
#define C_INIT 0.15200309344504997f   // log2(1/0.9), folded into MFMA C-init
#define QSCALE 0.18033688011112042f   // 0.125 * log2(e)

typedef __attribute__((ext_vector_type(8))) _Float16 f16x8;
typedef __attribute__((ext_vector_type(4))) _Float16 f16x4;
typedef __attribute__((ext_vector_type(4))) float f32x4;

#define MFMA32 __builtin_amdgcn_mfma_f32_16x16x32_f16   // K=32, A/B = f16x8
#define MFMA16 __builtin_amdgcn_mfma_f32_16x16x16f16    // K=16, A/B = f16x4

__device__ __forceinline__ uint32_t rotl1(uint32_t x, int r) {
    // single v_alignbit_b32: rotl(x,r) = ((x:x) >> (32-r))
    return __builtin_amdgcn_alignbit(x, x, 32 - r);
}

// JAX partitionable threefry, key (0,42), counter (0,i), out = x0^x1.
// (bit-exact verified rounds 2-10). ~71 VALU ops — the irreducible cost.
__device__ __forceinline__ uint32_t tf_bits(uint32_t i) {
    const uint32_t k1 = 42u, k2 = 0x1BD11BF0u;
    uint32_t x0 = 0u, x1 = i + k1;
#define TF_R(r) { x0 += x1; x1 = rotl1(x1, (r)); x1 ^= x0; }
    TF_R(13) TF_R(15) TF_R(26) TF_R(6)
    x0 += k1; x1 += k2 + 1u;
    TF_R(17) TF_R(29) TF_R(16) TF_R(24)
    x0 += k2; x1 += 2u;
    TF_R(13) TF_R(15) TF_R(26) TF_R(6)
    x1 += k1 + 3u;
    TF_R(17) TF_R(29) TF_R(16) TF_R(24)
    x0 += k1; x1 += k2 + 4u;
    TF_R(13) TF_R(15) TF_R(26) TF_R(6)
    x0 += k2; x1 += 5u;
#undef TF_R
    return x0 ^ x1;
}

// Fused flash-attention + bit-exact JAX dropout.
// R7 structure (single-buffer LDS K/V, P in registers as 16x16x16 fragments)
// + split-K (HALVES=2) + softmax denominator accumulated on the MATRIX pipe.
template<int HALVES>
__global__ __launch_bounds__(256, 4)
void attn_kernel(const float* __restrict__ Q, const float* __restrict__ K,
                 const float* __restrict__ V, float* __restrict__ O,
                 float* __restrict__ W) {
    constexpr int NT = 32 / HALVES;
    __shared__ __align__(16) _Float16 Kh[64][72];   // K tile [t][d]
    __shared__ __align__(16) _Float16 Vh[64][72];   // V^T tile [dd][t]

    const int tid  = threadIdx.x;
    const int lane = tid & 63;
    const int wid  = tid >> 6;
    const int g    = lane >> 4;
    const int sl   = lane & 15;

    const int bid  = blockIdx.x;
    const int half = bid / 768;
    const int bid2 = bid % 768;
    const int qb = bid2 & 31;
    const int bh = bid2 >> 5;
    const int h  = bh % H_;
    const int b  = bh / H_;
    const int kt0 = half * NT;

    const int s = qb * 64 + wid * 16 + sl;
    const size_t kvbase = (size_t)b * S_ * HD_ + (size_t)h * D_;

    // ---- Q fragment (B-operand of QK), scale 0.125*log2e, fp16 hi/lo ----
    f16x8 qh[2], ql[2];
    {
        const float* qp = Q + ((size_t)(b * S_ + s) * H_ + h) * D_;
#pragma unroll
        for (int ks = 0; ks < 2; ++ks) {
            int d0 = 32 * ks + 8 * g;
            float4 f0 = *reinterpret_cast<const float4*>(qp + d0);
            float4 f1 = *reinterpret_cast<const float4*>(qp + d0 + 4);
            float ff[8] = {f0.x, f0.y, f0.z, f0.w, f1.x, f1.y, f1.z, f1.w};
#pragma unroll
            for (int j = 0; j < 8; ++j) {
                float f = ff[j] * QSCALE;
                _Float16 hi = (_Float16)f;
                qh[ks][j] = hi;
                ql[ks][j] = (_Float16)(f - (float)hi);
            }
        }
    }

    // staging maps
    const int ktK = tid >> 2;            // K row t, 4 threads/row
    const int kd0 = (tid & 3) * 16;      // 16 consecutive d
    const int vdd = (tid & 31) * 2;      // V: dd pair
    const int vt0 = (tid >> 5) * 8;      // V: 8 consecutive t

    float4 kreg0, kreg1, kreg2, kreg3;
    float2 vreg[8];

#define LOADTILE(ktg_) do {                                                         \
        const float* kp = K + kvbase + (size_t)((ktg_) * 64 + ktK) * HD_ + kd0;     \
        kreg0 = *reinterpret_cast<const float4*>(kp);                               \
        kreg1 = *reinterpret_cast<const float4*>(kp + 4);                           \
        kreg2 = *reinterpret_cast<const float4*>(kp + 8);                           \
        kreg3 = *reinterpret_cast<const float4*>(kp + 12);                          \
        const float* vp = V + kvbase + (size_t)((ktg_) * 64 + vt0) * HD_ + vdd;     \
        _Pragma("unroll")                                                           \
        for (int j = 0; j < 8; ++j) vreg[j] = *reinterpret_cast<const float2*>(vp + j * HD_); \
    } while (0)

    LOADTILE(kt0);

    f32x4 outacc[4];
#pragma unroll
    for (int m = 0; m < 4; ++m) outacc[m] = (f32x4){0.f, 0.f, 0.f, 0.f};
    f32x4 Lacc = (f32x4){0.f, 0.f, 0.f, 0.f};   // denominator, on the matrix pipe
    f16x4 onesA;
#pragma unroll
    for (int r = 0; r < 4; ++r) onesA[r] = (_Float16)1.0f;

    const uint32_t rowbase = ((uint32_t)(bh * S_ + s)) << 11;

    for (int ktl = 0; ktl < NT; ++ktl) {
        const int ktg = kt0 + ktl;
        if (ktl) __syncthreads();
        // ---- staged regs -> LDS (fp16) ----
        {
            float ff[16] = {kreg0.x, kreg0.y, kreg0.z, kreg0.w,
                            kreg1.x, kreg1.y, kreg1.z, kreg1.w,
                            kreg2.x, kreg2.y, kreg2.z, kreg2.w,
                            kreg3.x, kreg3.y, kreg3.z, kreg3.w};
            f16x8 h0, h1;
#pragma unroll
            for (int j = 0; j < 8; ++j) { h0[j] = (_Float16)ff[j]; h1[j] = (_Float16)ff[8 + j]; }
            *reinterpret_cast<f16x8*>(&Kh[ktK][kd0])     = h0;
            *reinterpret_cast<f16x8*>(&Kh[ktK][kd0 + 8]) = h1;
            f16x8 v0, v1;
#pragma unroll
            for (int j = 0; j < 8; ++j) { v0[j] = (_Float16)vreg[j].x; v1[j] = (_Float16)vreg[j].y; }
            *reinterpret_cast<f16x8*>(&Vh[vdd][vt0])     = v0;
            *reinterpret_cast<f16x8*>(&Vh[vdd + 1][vt0]) = v1;
        }
        __syncthreads();
        if (ktl + 1 < NT) LOADTILE(ktg + 1);   // overlap HBM/L2 latency with compute

        // ---- QK^T (swapped): sc[m][r] = log2e*S^T[t][s] + C, t=16m+4g+r, s=sl ----
        f32x4 sc[4];
#pragma unroll
        for (int m = 0; m < 4; ++m) sc[m] = (f32x4){C_INIT, C_INIT, C_INIT, C_INIT};
#pragma unroll
        for (int m = 0; m < 4; ++m) {
#pragma unroll
            for (int ks = 0; ks < 2; ++ks) {
                f16x8 ah = *reinterpret_cast<const f16x8*>(&Kh[16 * m + sl][8 * g + 32 * ks]);
                sc[m] = MFMA32(ah, qh[ks], sc[m], 0, 0, 0);
                sc[m] = MFMA32(ah, ql[ks], sc[m], 0, 0, 0);
            }
        }

        // ---- exp2 + threefry dropout + fp16 pack; L-sum and AV on matrix pipe ----
        const uint32_t fb = rowbase + (uint32_t)(ktg * 64);
#pragma unroll
        for (int m = 0; m < 4; ++m) {
            int t0 = 16 * m + 4 * g;
            f16x4 eh, w;
#pragma unroll
            for (int r = 0; r < 4; ++r) {
                float e = exp2f(sc[m][r]);          // = exp(score)/0.9
                eh[r] = (_Float16)e;                // RNE fp16 = astype(f16)
                uint32_t bits = tf_bits(fb + (uint32_t)(t0 + r));
                w[r] = (bits < KEEP_HI) ? eh[r] : (_Float16)0.0f;
            }
            // denominator: C[row][s] += sum_k 1 * eh[k][s]  (A=ones: layout-proof;
            // MFMA also does the cross-lane-group k-sum -> no epilogue shuffles)
            Lacc = MFMA16(onesA, eh, Lacc, 0, 0, 0);
#pragma unroll
            for (int md = 0; md < 4; ++md) {
                f16x4 va = *reinterpret_cast<const f16x4*>(&Vh[16 * md + sl][16 * m + 4 * g]);
                outacc[md] = MFMA16(va, w, outacc[md], 0, 0, 0);
            }
        }
    }
#undef LOADTILE

    const float lsum = Lacc[0];   // = sum_t exp(score)/0.9 over this half (all rows of Lacc equal)

    if (HALVES == 1) {
        const float invL = 1.0f / (0.9f * lsum);
        float* op = O + ((size_t)bh * S_ + s) * D_;
#pragma unroll
        for (int m = 0; m < 4; ++m) {
            int dd0 = 16 * m + 4 * g;
            float4 f = make_float4(outacc[m][0] * invL, outacc[m][1] * invL,
                                   outacc[m][2] * invL, outacc[m][3] * invL);
            *reinterpret_cast<float4*>(op + dd0) = f;
        }
    } else {
        float* wp = W + ((size_t)(half * 24 + bh) * S_ + s) * 68;
#pragma unroll
        for (int m = 0; m < 4; ++m) {
            int dd0 = 16 * m + 4 * g;
            float4 f = make_float4(outacc[m][0], outacc[m][1], outacc[m][2], outacc[m][3]);
            *reinterpret_cast<float4*>(wp + dd0) = f;
        }
        if (g == 0) wp[64] = lsum;
    }
}

__global__ __launch_bounds__(256)
void combine_kernel(const float* __restrict__ W, float* __restrict__ O) {
    const int row = blockIdx.x * 4 + (threadIdx.x >> 6);   // bh*2048 + s
    const int dd  = threadIdx.x & 63;
    const float* w0 = W + (size_t)row * 68;
    const float* w1 = W + ((size_t)(24 * 2048) + row) * 68;
    const float L = w0[64] + w1[64];                        // = L_true/0.9
    const float scale = 1.0f / (0.9f * L);
    O[(size_t)row * 64 + dd] = (w0[dd] + w1[dd]) * scale;
}

extern "C" void kernel_launch(void* const* d_in, const int* in_sizes, int n_in,
                              void* d_out, int out_size, void* d_ws, size_t ws_size,
                              hipStream_t stream) {
    const float* Q = (const float*)d_in[0];
    const float* K = (const float*)d_in[1];
    const float* V = (const float*)d_in[2];
    float* O = (float*)d_out;
    (void)in_sizes; (void)n_in; (void)out_size;

    const size_t ws_need = (size_t)2 * 24 * 2048 * 68 * sizeof(float);  // 26.7 MB
    if (d_ws && ws_size >= ws_need) {
        float* W = (float*)d_ws;
        attn_kernel<2><<<dim3(1536), dim3(256), 0, stream>>>(Q, K, V, O, W);
        combine_kernel<<<dim3(24 * 2048 / 4), dim3(256), 0, stream>>>(W, O);
    } else {
        attn_kernel<1><<<dim3(768), dim3(256), 0, stream>>>(Q, K, V, O, nullptr);
    }
}

// Round 12
// 231.272 us; speedup vs baseline: 1.4553x; 1.0241x over previous
//
#include <hip/hip_runtime.h>
#include <stdint.h>

#define B_ 2
#define S_ 2048
#define H_ 12
#define D_ 64
#define HD_ (H_ * D_)                 // 768
#define KEEP_HI 3865470464u           // 7549747u << 9 : bits < this  <=>  uniform < 0.9
#define C_INIT 0.15200309344504997f   // log2(1/0.9), folded into MFMA C-init
#define QSCALE 0.18033688011112042f   // 0.125 * log2(e)

typedef __attribute__((ext_vector_type(8))) _Float16 f16x8;
typedef __attribute__((ext_vector_type(4))) _Float16 f16x4;
typedef __attribute__((ext_vector_type(4))) float f32x4;

#define MFMA32 __builtin_amdgcn_mfma_f32_16x16x32_f16   // K=32, A/B = f16x8

// JAX partitionable threefry, key (0,42), counter (0,i), out = x0^x1.
// (bit-exact verified rounds 2-11). ~73 VALU ops/element — the irreducible cost.
__device__ __forceinline__ uint32_t tf_bits(uint32_t i) {
    const uint32_t k1 = 42u, k2 = 0x1BD11BF0u;
    uint32_t x0 = 0u, x1 = i + k1;
#define TF_R(r) { x0 += x1; x1 = __builtin_rotateleft32(x1, (r)); x1 ^= x0; }
    TF_R(13) TF_R(15) TF_R(26) TF_R(6)
    x0 += k1; x1 += k2 + 1u;
    TF_R(17) TF_R(29) TF_R(16) TF_R(24)
    x0 += k2; x1 += 2u;
    TF_R(13) TF_R(15) TF_R(26) TF_R(6)
    x1 += k1 + 3u;
    TF_R(17) TF_R(29) TF_R(16) TF_R(24)
    x0 += k1; x1 += k2 + 4u;
    TF_R(13) TF_R(15) TF_R(26) TF_R(6)
    x0 += k2; x1 += 5u;
#undef TF_R
    return x0 ^ x1;
}

template<int HALVES>
__global__ __launch_bounds__(256, 4)
void attn_kernel(const float* __restrict__ Q, const float* __restrict__ K,
                 const float* __restrict__ V, float* __restrict__ O,
                 float* __restrict__ W) {
    constexpr int NT = 32 / HALVES;
    __shared__ __align__(16) _Float16 Kh[64][72];        // K tile [t][d]
    __shared__ __align__(16) _Float16 Vh[64][72];        // V^T tile [dd][t]
    __shared__ __align__(16) _Float16 PSm[4][16][72];    // per-wave P [s][t]

    const int tid  = threadIdx.x;
    const int lane = tid & 63;
    const int wid  = tid >> 6;
    const int g    = lane >> 4;
    const int sl   = lane & 15;

    const int bid  = blockIdx.x;
    const int half = bid / 768;
    const int bid2 = bid % 768;
    const int qb = bid2 & 31;
    const int bh = bid2 >> 5;
    const int h  = bh % H_;
    const int b  = bh / H_;
    const int kt0 = half * NT;

    const int s = qb * 64 + wid * 16 + sl;
    const size_t kvbase = (size_t)b * S_ * HD_ + (size_t)h * D_;

    // ---- Q fragment (B-operand), scale 0.125*log2e, fp16 hi/lo ----
    f16x8 qh[2], ql[2];
    {
        const float* qp = Q + ((size_t)(b * S_ + s) * H_ + h) * D_;
#pragma unroll
        for (int ks = 0; ks < 2; ++ks) {
            int d0 = 32 * ks + 8 * g;
            float4 f0 = *reinterpret_cast<const float4*>(qp + d0);
            float4 f1 = *reinterpret_cast<const float4*>(qp + d0 + 4);
            float ff[8] = {f0.x, f0.y, f0.z, f0.w, f1.x, f1.y, f1.z, f1.w};
#pragma unroll
            for (int j = 0; j < 8; ++j) {
                float f = ff[j] * QSCALE;
                _Float16 hi = (_Float16)f;
                qh[ks][j] = hi;
                ql[ks][j] = (_Float16)(f - (float)hi);
            }
        }
    }

    // staging maps
    const int ktK = tid >> 2;            // K row t, 4 threads/row
    const int kd0 = (tid & 3) * 16;      // 16 consecutive d
    const int vdd = (tid & 31) * 2;      // V: dd pair
    const int vt0 = (tid >> 5) * 8;      // V: 8 consecutive t

    float4 kreg0, kreg1, kreg2, kreg3;
    float2 vreg[8];

#define LOADTILE(ktg_) do {                                                         \
        const float* kp = K + kvbase + (size_t)((ktg_) * 64 + ktK) * HD_ + kd0;     \
        kreg0 = *reinterpret_cast<const float4*>(kp);                               \
        kreg1 = *reinterpret_cast<const float4*>(kp + 4);                           \
        kreg2 = *reinterpret_cast<const float4*>(kp + 8);                           \
        kreg3 = *reinterpret_cast<const float4*>(kp + 12);                          \
        const float* vp = V + kvbase + (size_t)((ktg_) * 64 + vt0) * HD_ + vdd;     \
        _Pragma("unroll")                                                           \
        for (int j = 0; j < 8; ++j) vreg[j] = *reinterpret_cast<const float2*>(vp + j * HD_); \
    } while (0)

    LOADTILE(kt0);

    float lrun = 0.f;
    f32x4 outacc[4];
#pragma unroll
    for (int m = 0; m < 4; ++m) outacc[m] = (f32x4){0.f, 0.f, 0.f, 0.f};

    const uint32_t rowbase = ((uint32_t)(bh * S_ + s)) << 11;

    for (int ktl = 0; ktl < NT; ++ktl) {
        const int ktg = kt0 + ktl;
        if (ktl) __syncthreads();
        // ---- staged regs -> LDS (fp16) ----
        {
            float ff[16] = {kreg0.x, kreg0.y, kreg0.z, kreg0.w,
                            kreg1.x, kreg1.y, kreg1.z, kreg1.w,
                            kreg2.x, kreg2.y, kreg2.z, kreg2.w,
                            kreg3.x, kreg3.y, kreg3.z, kreg3.w};
            f16x8 h0, h1;
#pragma unroll
            for (int j = 0; j < 8; ++j) { h0[j] = (_Float16)ff[j]; h1[j] = (_Float16)ff[8 + j]; }
            *reinterpret_cast<f16x8*>(&Kh[ktK][kd0])     = h0;
            *reinterpret_cast<f16x8*>(&Kh[ktK][kd0 + 8]) = h1;
            f16x8 v0, v1;
#pragma unroll
            for (int j = 0; j < 8; ++j) { v0[j] = (_Float16)vreg[j].x; v1[j] = (_Float16)vreg[j].y; }
            *reinterpret_cast<f16x8*>(&Vh[vdd][vt0])     = v0;
            *reinterpret_cast<f16x8*>(&Vh[vdd + 1][vt0]) = v1;
        }
        __syncthreads();
        if (ktl + 1 < NT) LOADTILE(ktg + 1);   // overlap HBM/L2 latency with compute

        // ---- QK^T (swapped): sc[m][r] = log2e*S^T[t][s] + C, t=16m+4g+r, s=sl ----
        f32x4 sc[4];
#pragma unroll
        for (int m = 0; m < 4; ++m) sc[m] = (f32x4){C_INIT, C_INIT, C_INIT, C_INIT};
#pragma unroll
        for (int m = 0; m < 4; ++m) {
#pragma unroll
            for (int ks = 0; ks < 2; ++ks) {
                f16x8 ah = *reinterpret_cast<const f16x8*>(&Kh[16 * m + sl][8 * g + 32 * ks]);
                sc[m] = MFMA32(ah, qh[ks], sc[m], 0, 0, 0);
                sc[m] = MFMA32(ah, ql[ks], sc[m], 0, 0, 0);
            }
        }

        // ---- fused exp2 + threefry dropout + fp16 pack (no max-tracking) ----
        const uint32_t fb = rowbase + (uint32_t)(ktg * 64);
#pragma unroll
        for (int m = 0; m < 4; ++m) {
            int t0 = 16 * m + 4 * g;
            f16x4 w;
#pragma unroll
            for (int r = 0; r < 4; ++r) {
                float e = exp2f(sc[m][r]);          // = exp(score)/0.9
                lrun += e;
                uint32_t bits = tf_bits(fb + (uint32_t)(t0 + r));
                float pf = (bits < KEEP_HI) ? e : 0.0f;
                w[r] = (_Float16)pf;                // RNE fp16, matches astype(f16)
            }
            *reinterpret_cast<f16x4*>(&PSm[wid][sl][t0]) = w;
        }

        // ---- AV (swapped): out^T[dd][s] += V^T_frag * P_frag ----
        f16x8 pb0 = *reinterpret_cast<const f16x8*>(&PSm[wid][sl][8 * g]);
        f16x8 pb1 = *reinterpret_cast<const f16x8*>(&PSm[wid][sl][8 * g + 32]);
#pragma unroll
        for (int m = 0; m < 4; ++m) {
            f16x8 vh0 = *reinterpret_cast<const f16x8*>(&Vh[16 * m + sl][8 * g]);
            f16x8 vh1 = *reinterpret_cast<const f16x8*>(&Vh[16 * m + sl][8 * g + 32]);
            outacc[m] = MFMA32(vh0, pb0, outacc[m], 0, 0, 0);
            outacc[m] = MFMA32(vh1, pb1, outacc[m], 0, 0, 0);
        }
    }
#undef LOADTILE

    // ---- row-sum L across the 4 lane groups ----
    lrun += __shfl_xor(lrun, 16);
    lrun += __shfl_xor(lrun, 32);

    if (HALVES == 1) {
        const float invL = 1.0f / (0.9f * lrun);   // lrun = L/0.9
        float* op = O + ((size_t)bh * S_ + s) * D_;
#pragma unroll
        for (int m = 0; m < 4; ++m) {
            int dd0 = 16 * m + 4 * g;
            float4 f = make_float4(outacc[m][0] * invL, outacc[m][1] * invL,
                                   outacc[m][2] * invL, outacc[m][3] * invL);
            *reinterpret_cast<float4*>(op + dd0) = f;
        }
    } else {
        float* wp = W + ((size_t)(half * 24 + bh) * S_ + s) * 68;
#pragma unroll
        for (int m = 0; m < 4; ++m) {
            int dd0 = 16 * m + 4 * g;
            float4 f = make_float4(outacc[m][0], outacc[m][1], outacc[m][2], outacc[m][3]);
            *reinterpret_cast<float4*>(wp + dd0) = f;
        }
        if (g == 0) wp[64] = lrun;
    }
}

__global__ __launch_bounds__(256)
void combine_kernel(const float* __restrict__ W, float* __restrict__ O) {
    const int row = blockIdx.x * 4 + (threadIdx.x >> 6);   // bh*2048 + s
    const int dd  = threadIdx.x & 63;
    const float* w0 = W + (size_t)row * 68;
    const float* w1 = W + ((size_t)(24 * 2048) + row) * 68;
    const float L = w0[64] + w1[64];                        // = L_true/0.9
    const float scale = 1.0f / (0.9f * L);
    O[(size_t)row * 64 + dd] = (w0[dd] + w1[dd]) * scale;
}

extern "C" void kernel_launch(void* const* d_in, const int* in_sizes, int n_in,
                              void* d_out, int out_size, void* d_ws, size_t ws_size,
                              hipStream_t stream) {
    const float* Q = (const float*)d_in[0];
    const float* K = (const float*)d_in[1];
    const float* V = (const float*)d_in[2];
    float* O = (float*)d_out;
    (void)in_sizes; (void)n_in; (void)out_size;

    const size_t ws_need = (size_t)2 * 24 * 2048 * 68 * sizeof(float);  // 26.7 MB
    if (d_ws && ws_size >= ws_need) {
        float* W = (float*)d_ws;
        attn_kernel<2><<<dim3(1536), dim3(256), 0, stream>>>(Q, K, V, O, W);
        combine_kernel<<<dim3(24 * 2048 / 4), dim3(256), 0, stream>>>(W, O);
    } else {
        attn_kernel<1><<<dim3(768), dim3(256), 0, stream>>>(Q, K, V, O, nullptr);
    }
}